// Round 2
// baseline (27.046 us; speedup 1.0000x reference)
//
#include <hip/hip_runtime.h>

// B=16 rows. Per row: base = logits + noise; select top K=1024 of N=4096;
// forward output == hard * x exactly (straight-through softmax cancels).
//
// Design: ONE WAVE per row. 64 lanes x 64 keys held in VGPRs. The K-th
// largest key is found by a 32-step bitwise radix search where the count
// "#keys >= cand" is computed as sum_j popcount(ballot(key[j] >= cand)):
// one v_cmp per key (VALU) + s_bcnt1/s_add on the scalar unit in parallel.
// No LDS, no __syncthreads, no shuffle-reduce in the hot loop.
#define BB 16
#define NN 4096
#define KK 1024
#define PT 64   // elements per lane (single 64-lane wave per row)

// Monotonic float->uint key: larger key <=> larger float (no NaNs here).
__device__ __forceinline__ unsigned fkey(float f) {
    unsigned u = __float_as_uint(f);
    return (u & 0x80000000u) ? ~u : (u | 0x80000000u);
}

__global__ __launch_bounds__(64) void gumbel_topk_mask(
    const float* __restrict__ x,
    const float* __restrict__ logits,
    const float* __restrict__ noise,
    float* __restrict__ out)
{
    const int b = blockIdx.x;
    const int t = threadIdx.x;            // lane 0..63
    const size_t row = (size_t)b * NN;
    const int n0 = t * PT;                // lane-major contiguous chunk

    // ---- load keys into registers (float4-vectorized) ----
    unsigned key[PT];
    {
        const float4* lg4 = (const float4*)(logits + n0);
        const float4* nz4 = (const float4*)(noise + row + n0);
        #pragma unroll
        for (int q = 0; q < PT / 4; ++q) {
            float4 l = lg4[q], z = nz4[q];
            key[4*q+0] = fkey(l.x + z.x);
            key[4*q+1] = fkey(l.y + z.y);
            key[4*q+2] = fkey(l.z + z.z);
            key[4*q+3] = fkey(l.w + z.w);
        }
    }

    // ---- bitwise radix search for the K-th largest key ----
    // Invariant: count(key >= pfx) >= K. Early exit when a candidate splits
    // at exactly K (then {key >= cand} IS the top-K set).
    unsigned pfx = 0u;
    #pragma unroll 1
    for (int bit = 31; bit >= 0; --bit) {
        const unsigned cand = pfx | (1u << bit);
        int cnt = 0;
        #pragma unroll
        for (int j = 0; j < PT; ++j)
            cnt += __popcll(__ballot(key[j] >= cand));
        if (cnt >= KK) {
            pfx = cand;
            if (cnt == KK) break;
        }
    }
    const unsigned T = pfx;

    // ---- counts for tie handling ----
    int cnt_gt = 0;   // wave-uniform (ballot-derived)
    int ecnt   = 0;   // per-lane count of equals in my chunk
    #pragma unroll
    for (int j = 0; j < PT; ++j) {
        cnt_gt += __popcll(__ballot(key[j] > T));
        ecnt   += (key[j] == T) ? 1 : 0;
    }
    const int rem = KK - cnt_gt;  // equals accepted, lowest global index first

    // Exclusive prefix sum of ecnt across lanes. Global index order is
    // lane-major (all of lane t's indices precede lane t+1's), so this gives
    // the number of equal-valued elements preceding my chunk.
    int inc = ecnt;
    #pragma unroll
    for (int off = 1; off < 64; off <<= 1) {
        int v = __shfl_up(inc, off, 64);
        if (t >= off) inc += v;
    }
    int r = inc - ecnt;

    // ---- emit hard * x ----
    const float4* x4 = (const float4*)(x + row + n0);
    float4*       o4 = (float4*)(out + row + n0);
    #pragma unroll
    for (int q = 0; q < PT / 4; ++q) {
        float4 xv = x4[q];
        unsigned k0 = key[4*q+0], k1 = key[4*q+1],
                 k2 = key[4*q+2], k3 = key[4*q+3];
        bool s0 = (k0 > T) || (k0 == T && (r++ < rem));
        bool s1 = (k1 > T) || (k1 == T && (r++ < rem));
        bool s2 = (k2 > T) || (k2 == T && (r++ < rem));
        bool s3 = (k3 > T) || (k3 == T && (r++ < rem));
        float4 ov;
        ov.x = s0 ? xv.x : 0.0f;
        ov.y = s1 ? xv.y : 0.0f;
        ov.z = s2 ? xv.z : 0.0f;
        ov.w = s3 ? xv.w : 0.0f;
        o4[q] = ov;
    }
}

extern "C" void kernel_launch(void* const* d_in, const int* in_sizes, int n_in,
                              void* d_out, int out_size, void* d_ws, size_t ws_size,
                              hipStream_t stream) {
    const float* x      = (const float*)d_in[0];   // [B, N]
    const float* logits = (const float*)d_in[1];   // [N]
    const float* noise  = (const float*)d_in[2];   // [B, N]
    float* out = (float*)d_out;                    // [B, N]
    (void)in_sizes; (void)n_in; (void)out_size; (void)d_ws; (void)ws_size;
    gumbel_topk_mask<<<BB, 64, 0, stream>>>(x, logits, noise, out);
}

// Round 3
// 26.529 us; speedup vs baseline: 1.0195x; 1.0195x over previous
//
#include <hip/hip_runtime.h>

// B=16 rows. Per row: base = logits + noise; select top K=1024 of N=4096;
// forward output == hard * x exactly (straight-through softmax cancels).
//
// ONE WAVE per row, 64 keys/lane in VGPRs. K-th largest key via 32-step
// bitwise radix search; count(#keys >= cand) = sum_j popcount(ballot(...)):
// v_cmp on VALU + s_bcnt1/s_add on the parallel scalar pipe. No LDS, no
// barriers. This round: x is prefetched BEFORE the search so its HBM
// round-trip hides under the search compute (epilogue then has zero loads).
#define BB 16
#define NN 4096
#define KK 1024
#define PT 64   // elements per lane

// Monotonic float->uint key: larger key <=> larger float (no NaNs here).
__device__ __forceinline__ unsigned fkey(float f) {
    unsigned u = __float_as_uint(f);
    return (u & 0x80000000u) ? ~u : (u | 0x80000000u);
}

__global__ __launch_bounds__(64) void gumbel_topk_mask(
    const float* __restrict__ x,
    const float* __restrict__ logits,
    const float* __restrict__ noise,
    float* __restrict__ out)
{
    const int b = blockIdx.x;
    const int t = threadIdx.x;            // lane 0..63
    const size_t row = (size_t)b * NN;
    const int n0 = t * PT;                // lane-major contiguous chunk

    // ---- load keys into registers; issue x prefetch alongside ----
    unsigned key[PT];
    float4 xv[PT / 4];
    {
        const float4* lg4 = (const float4*)(logits + n0);
        const float4* nz4 = (const float4*)(noise + row + n0);
        const float4* x4  = (const float4*)(x + row + n0);
        #pragma unroll
        for (int q = 0; q < PT / 4; ++q) {
            float4 l = lg4[q], z = nz4[q];
            xv[q] = x4[q];                // in flight during the search
            key[4*q+0] = fkey(l.x + z.x);
            key[4*q+1] = fkey(l.y + z.y);
            key[4*q+2] = fkey(l.z + z.z);
            key[4*q+3] = fkey(l.w + z.w);
        }
    }

    // ---- bitwise radix search for the K-th largest key ----
    // Invariant: count(key >= pfx) >= K. Early exit when a candidate splits
    // at exactly K (then {key >= cand} IS the top-K set).
    unsigned pfx = 0u;
    #pragma unroll 1
    for (int bit = 31; bit >= 0; --bit) {
        const unsigned cand = pfx | (1u << bit);
        int cnt = 0;
        #pragma unroll
        for (int j = 0; j < PT; ++j)
            cnt += __popcll(__ballot(key[j] >= cand));
        if (cnt >= KK) {
            pfx = cand;
            if (cnt == KK) break;
        }
    }
    const unsigned T = pfx;

    // ---- counts for exact tie handling ----
    int cnt_gt = 0;   // wave-uniform (ballot-derived)
    int ecnt   = 0;   // per-lane equals in my chunk
    #pragma unroll
    for (int j = 0; j < PT; ++j) {
        cnt_gt += __popcll(__ballot(key[j] > T));
        ecnt   += (key[j] == T) ? 1 : 0;
    }
    const int rem = KK - cnt_gt;  // equals accepted, lowest global index first

    // Exclusive prefix of ecnt across lanes (global order is lane-major).
    int inc = ecnt;
    #pragma unroll
    for (int off = 1; off < 64; off <<= 1) {
        int v = __shfl_up(inc, off, 64);
        if (t >= off) inc += v;
    }
    int r = inc - ecnt;

    // ---- emit hard * x (x already in registers) ----
    float4* o4 = (float4*)(out + row + n0);
    #pragma unroll
    for (int q = 0; q < PT / 4; ++q) {
        unsigned k0 = key[4*q+0], k1 = key[4*q+1],
                 k2 = key[4*q+2], k3 = key[4*q+3];
        bool s0 = (k0 > T) || (k0 == T && (r++ < rem));
        bool s1 = (k1 > T) || (k1 == T && (r++ < rem));
        bool s2 = (k2 > T) || (k2 == T && (r++ < rem));
        bool s3 = (k3 > T) || (k3 == T && (r++ < rem));
        float4 ov;
        ov.x = s0 ? xv[q].x : 0.0f;
        ov.y = s1 ? xv[q].y : 0.0f;
        ov.z = s2 ? xv[q].z : 0.0f;
        ov.w = s3 ? xv[q].w : 0.0f;
        o4[q] = ov;
    }
}

extern "C" void kernel_launch(void* const* d_in, const int* in_sizes, int n_in,
                              void* d_out, int out_size, void* d_ws, size_t ws_size,
                              hipStream_t stream) {
    const float* x      = (const float*)d_in[0];   // [B, N]
    const float* logits = (const float*)d_in[1];   // [N]
    const float* noise  = (const float*)d_in[2];   // [B, N]
    float* out = (float*)d_out;                    // [B, N]
    (void)in_sizes; (void)n_in; (void)out_size; (void)d_ws; (void)ws_size;
    gumbel_topk_mask<<<BB, 64, 0, stream>>>(x, logits, noise, out);
}